// Round 1
// baseline (1000.673 us; speedup 1.0000x reference)
//
#include <hip/hip_runtime.h>
#include <math.h>

// Problem constants
#define DD     2048   // model dim
#define EE     64     // num experts
#define NTOK   8192   // B*T
#define KSPLIT 16
#define KR     (DD / KSPLIT)   // 128 k per split

// Output layout (all read back as float32 by harness):
//   router_probs [4,2048,64]  -> 524288 floats @ 0
//   top_k_indices [4,2048,2]  -> 16384 floats  @ 524288
//   exp_mask [2, 8192, 64]    -> 1048576 floats @ 540672
#define PROB_OFF 0
#define IDX_OFF  524288
#define MASK_OFF 540672
#define MASK_K_STRIDE (NTOK * EE)   // 524288

// ---------------------------------------------------------------------------
// Kernel 1: partial GEMM. One wave (64 threads) per block.
// lane <-> token; all 128 outputs (64 gate + 64 noise) accumulated in VGPRs.
// w_gate/w_noise accesses are wave-uniform -> scalar loads (s_load) feeding
// v_fmac with an SGPR operand. x streamed per-lane with dwordx4.
// Partials combined across the 16 k-splits via global f32 atomics.
// ---------------------------------------------------------------------------
__global__ __launch_bounds__(64) void router_gemm(
    const float* __restrict__ x,        // [NTOK][DD]
    const float* __restrict__ w_gate,   // [DD][EE]
    const float* __restrict__ w_noise,  // [DD][EE]
    float* __restrict__ logits)         // [NTOK][2*EE], pre-zeroed
{
  const int bid  = blockIdx.x;
  const int tg   = bid & 127;   // token group (consecutive blocks share w slice)
  const int ks   = bid >> 7;    // k split
  const int lane = threadIdx.x;
  const int t    = tg * 64 + lane;
  const int k0   = ks * KR;

  const float* __restrict__ xrow = x + (size_t)t * DD + k0;

  float accg[EE];
  float accn[EE];
#pragma unroll
  for (int e = 0; e < EE; ++e) { accg[e] = 0.0f; accn[e] = 0.0f; }

  for (int k = 0; k < KR; k += 4) {
    const float4 xv = *reinterpret_cast<const float4*>(xrow + k);
    const float* __restrict__ wgr = w_gate  + (size_t)(k0 + k) * EE;
    const float* __restrict__ wnr = w_noise + (size_t)(k0 + k) * EE;
#pragma unroll
    for (int r = 0; r < 4; ++r) {
      const float xs = (r == 0) ? xv.x : (r == 1) ? xv.y : (r == 2) ? xv.z : xv.w;
#pragma unroll
      for (int e = 0; e < EE; ++e) {
        accg[e] = fmaf(xs, wgr[r * EE + e], accg[e]);
        accn[e] = fmaf(xs, wnr[r * EE + e], accn[e]);
      }
    }
  }

  float* orow = logits + (size_t)t * (2 * EE);
#pragma unroll
  for (int e = 0; e < EE; ++e) {
    atomicAdd(orow + e,      accg[e]);
    atomicAdd(orow + EE + e, accn[e]);
  }
}

// ---------------------------------------------------------------------------
// Kernel 2: epilogue. One wave per token (4 tokens / 256-thread block).
// lane <-> expert. Stable softplus, noisy logits, butterfly top-2 with
// jax.lax.top_k tie semantics (descending value, ascending index on ties),
// softmax over the 2 kept logits, scatter probs + indices + one-hot masks.
// ---------------------------------------------------------------------------
__global__ __launch_bounds__(256) void router_epilogue(
    const float* __restrict__ logits,    // [NTOK][2*EE]
    const float* __restrict__ noise_eps, // [NTOK][EE]
    float* __restrict__ out)
{
  const int t    = blockIdx.x * 4 + (threadIdx.x >> 6);
  const int lane = threadIdx.x & 63;

  const float g    = logits[(size_t)t * (2 * EE) + lane];
  const float nraw = logits[(size_t)t * (2 * EE) + EE + lane];
  const float ep   = noise_eps[(size_t)t * EE + lane];

  // softplus(nraw) = max(nraw,0) + log1p(exp(-|nraw|))
  const float sp = fmaxf(nraw, 0.0f) + log1pf(expf(-fabsf(nraw)));
  const float z  = fmaf(sp, ep, g);

  // top-1 (butterfly; all lanes converge to the same result)
  float v1 = z; int i1 = lane;
#pragma unroll
  for (int off = 32; off >= 1; off >>= 1) {
    const float ov = __shfl_xor(v1, off, 64);
    const int   oi = __shfl_xor(i1, off, 64);
    if (ov > v1 || (ov == v1 && oi < i1)) { v1 = ov; i1 = oi; }
  }
  // top-2: exclude winner
  float v2 = (lane == i1) ? -INFINITY : z; int i2 = lane;
#pragma unroll
  for (int off = 32; off >= 1; off >>= 1) {
    const float ov = __shfl_xor(v2, off, 64);
    const int   oi = __shfl_xor(i2, off, 64);
    if (ov > v2 || (ov == v2 && oi < i2)) { v2 = ov; i2 = oi; }
  }

  // softmax over [v1, v2] (v1 >= v2)
  const float e2   = expf(v2 - v1);
  const float denom = 1.0f + e2;
  const float p1 = 1.0f / denom;
  const float p2 = e2 / denom;

  // router_probs
  const float pr = (lane == i1) ? p1 : ((lane == i2) ? p2 : 0.0f);
  out[PROB_OFF + (size_t)t * EE + lane] = pr;

  // top_k_indices (as float; harness reads whole buffer as f32)
  if (lane == 0) {
    out[IDX_OFF + t * 2 + 0] = (float)i1;
    out[IDX_OFF + t * 2 + 1] = (float)i2;
  }

  // exp_mask [K, NTOK, EE]
  out[MASK_OFF + 0 * MASK_K_STRIDE + (size_t)t * EE + lane] = (lane == i1) ? 1.0f : 0.0f;
  out[MASK_OFF + 1 * MASK_K_STRIDE + (size_t)t * EE + lane] = (lane == i2) ? 1.0f : 0.0f;
}

// ---------------------------------------------------------------------------
extern "C" void kernel_launch(void* const* d_in, const int* in_sizes, int n_in,
                              void* d_out, int out_size, void* d_ws, size_t ws_size,
                              hipStream_t stream) {
  const float* x   = (const float*)d_in[0];
  const float* eps = (const float*)d_in[1];
  const float* wg  = (const float*)d_in[2];
  const float* wn  = (const float*)d_in[3];
  float* out = (float*)d_out;
  float* ws  = (float*)d_ws;   // [NTOK][128] partial logits, 4 MB

  // zero the accumulation workspace (re-poisoned to 0xAA before every launch)
  hipMemsetAsync(d_ws, 0, (size_t)NTOK * 2 * EE * sizeof(float), stream);

  router_gemm<<<dim3(128 * KSPLIT), dim3(64), 0, stream>>>(x, wg, wn, ws);
  router_epilogue<<<dim3(NTOK / 4), dim3(256), 0, stream>>>(ws, eps, out);
}

// Round 2
// 358.107 us; speedup vs baseline: 2.7943x; 2.7943x over previous
//
#include <hip/hip_runtime.h>
#include <math.h>

// Problem constants
#define DD    2048   // model dim
#define EE    64     // num experts
#define NTOK  8192   // B*T
#define TT    8      // tokens per wave

// Output layout (all read back as float32 by harness):
//   router_probs [4,2048,64]  -> 524288 floats @ 0
//   top_k_indices [4,2048,2]  -> 16384 floats  @ 524288
//   exp_mask [2, 8192, 64]    -> 1048576 floats @ 540672
#define PROB_OFF 0
#define IDX_OFF  524288
#define MASK_OFF 540672
#define MASK_K_STRIDE (NTOK * EE)   // 524288

// ---------------------------------------------------------------------------
// GEMM: lane = expert. w[k][lane] is a perfectly coalesced 256B vector load;
// x[t][k] is wave-uniform -> scalar loads (s_load) feeding v_fmac's src.
// 8 accumulators/lane only -> no spill. k-split partials to disjoint ws
// regions (plain coalesced stores, no atomics).
// Block = 256 thr = 4 waves: {gate,noise} x {2 token sub-tiles of 8}.
// Grid = (NTOK/16) * KSPLIT.
// ---------------------------------------------------------------------------
template <int KSPLIT>
__global__ __launch_bounds__(256) void router_gemm(
    const float* __restrict__ x,        // [NTOK][DD]
    const float* __restrict__ w_gate,   // [DD][EE]
    const float* __restrict__ w_noise,  // [DD][EE]
    float* __restrict__ part)           // [KSPLIT][NTOK][2*EE]
{
  constexpr int KR = DD / KSPLIT;

  const int wid  = threadIdx.x >> 6;   // 0..3
  const int lane = threadIdx.x & 63;   // expert
  const int mat  = wid & 1;            // 0 = gate, 1 = noise
  const int tsub = wid >> 1;           // 0..1

  const int tg = blockIdx.x % (NTOK / 16);
  const int ks = blockIdx.x / (NTOK / 16);
  const int tok0 = tg * 16 + tsub * TT;
  const int k0 = ks * KR;

  const float* __restrict__ W =
      (mat ? w_noise : w_gate) + (size_t)k0 * EE + lane;
  const float* __restrict__ xb = x + (size_t)tok0 * DD + k0;

  float acc[TT];
#pragma unroll
  for (int t = 0; t < TT; ++t) acc[t] = 0.0f;

  for (int k = 0; k < KR; k += 8) {
#pragma unroll
    for (int u = 0; u < 8; ++u) {
      const float wv = W[(size_t)(k + u) * EE];   // per-lane, coalesced
#pragma unroll
      for (int t = 0; t < TT; ++t) {
        // x address is lane-invariant -> scalar load
        acc[t] = fmaf(xb[(size_t)t * DD + (k + u)], wv, acc[t]);
      }
    }
  }

  float* o = part + ((size_t)ks * NTOK + tok0) * (2 * EE) + mat * EE + lane;
#pragma unroll
  for (int t = 0; t < TT; ++t) o[(size_t)t * (2 * EE)] = acc[t];
}

// ---------------------------------------------------------------------------
// Epilogue: one wave per token. Sum ksplit partials, softplus-noise, top-2
// (jax tie semantics: desc value, asc index), softmax over 2, scatter.
// ---------------------------------------------------------------------------
__global__ __launch_bounds__(256) void router_epilogue(
    const float* __restrict__ part,      // [ksplit][NTOK][2*EE]
    const float* __restrict__ noise_eps, // [NTOK][EE]
    float* __restrict__ out, int ksplit)
{
  const int t    = blockIdx.x * 4 + (threadIdx.x >> 6);
  const int lane = threadIdx.x & 63;

  float g = 0.0f, nraw = 0.0f;
  for (int s = 0; s < ksplit; ++s) {
    const float* p = part + ((size_t)s * NTOK + t) * (2 * EE);
    g    += p[lane];
    nraw += p[EE + lane];
  }
  const float ep = noise_eps[(size_t)t * EE + lane];

  // softplus(nraw) = max(nraw,0) + log1p(exp(-|nraw|))
  const float sp = fmaxf(nraw, 0.0f) + log1pf(expf(-fabsf(nraw)));
  const float z  = fmaf(sp, ep, g);

  // top-1 butterfly (all lanes converge)
  float v1 = z; int i1 = lane;
#pragma unroll
  for (int off = 32; off >= 1; off >>= 1) {
    const float ov = __shfl_xor(v1, off, 64);
    const int   oi = __shfl_xor(i1, off, 64);
    if (ov > v1 || (ov == v1 && oi < i1)) { v1 = ov; i1 = oi; }
  }
  // top-2: exclude winner
  float v2 = (lane == i1) ? -INFINITY : z; int i2 = lane;
#pragma unroll
  for (int off = 32; off >= 1; off >>= 1) {
    const float ov = __shfl_xor(v2, off, 64);
    const int   oi = __shfl_xor(i2, off, 64);
    if (ov > v2 || (ov == v2 && oi < i2)) { v2 = ov; i2 = oi; }
  }

  const float e2 = expf(v2 - v1);
  const float denom = 1.0f + e2;
  const float p1 = 1.0f / denom;
  const float p2 = e2 / denom;

  out[PROB_OFF + (size_t)t * EE + lane] =
      (lane == i1) ? p1 : ((lane == i2) ? p2 : 0.0f);

  if (lane == 0) {
    out[IDX_OFF + t * 2 + 0] = (float)i1;
    out[IDX_OFF + t * 2 + 1] = (float)i2;
  }

  out[MASK_OFF + 0 * MASK_K_STRIDE + (size_t)t * EE + lane] = (lane == i1) ? 1.0f : 0.0f;
  out[MASK_OFF + 1 * MASK_K_STRIDE + (size_t)t * EE + lane] = (lane == i2) ? 1.0f : 0.0f;
}

// ---------------------------------------------------------------------------
extern "C" void kernel_launch(void* const* d_in, const int* in_sizes, int n_in,
                              void* d_out, int out_size, void* d_ws, size_t ws_size,
                              hipStream_t stream) {
  const float* x   = (const float*)d_in[0];
  const float* eps = (const float*)d_in[1];
  const float* wg  = (const float*)d_in[2];
  const float* wn  = (const float*)d_in[3];
  float* out = (float*)d_out;
  float* ws  = (float*)d_ws;

  const size_t part_bytes = (size_t)NTOK * 2 * EE * sizeof(float);  // 4 MB per split

  int ksplit;
  if (ws_size >= 4 * part_bytes)      ksplit = 4;
  else if (ws_size >= 2 * part_bytes) ksplit = 2;
  else                                ksplit = 1;

  const dim3 block(256);
  const dim3 grid((NTOK / 16) * ksplit);

  if (ksplit == 4)      router_gemm<4><<<grid, block, 0, stream>>>(x, wg, wn, ws);
  else if (ksplit == 2) router_gemm<2><<<grid, block, 0, stream>>>(x, wg, wn, ws);
  else                  router_gemm<1><<<grid, block, 0, stream>>>(x, wg, wn, ws);

  router_epilogue<<<dim3(NTOK / 4), dim3(256), 0, stream>>>(ws, eps, out, ksplit);
}

// Round 3
// 258.029 us; speedup vs baseline: 3.8781x; 1.3879x over previous
//
#include <hip/hip_runtime.h>
#include <math.h>

// Problem constants
#define DD    2048   // model dim
#define EE    64     // num experts
#define NTOK  8192   // B*T

// Output layout (all read back as float32 by harness):
//   router_probs [4,2048,64]  -> 524288 floats @ 0
//   top_k_indices [4,2048,2]  -> 16384 floats  @ 524288
//   exp_mask [2, 8192, 64]    -> 1048576 floats @ 540672
#define PROB_OFF 0
#define IDX_OFF  524288
#define MASK_OFF 540672
#define MASK_K_STRIDE (NTOK * EE)   // 524288

// ---------------------------------------------------------------------------
// GEMM: ONE WAVE PER BLOCK so every x index is provably uniform -> s_load.
// lane layout: lanes 0..31 = gate, lanes 32..63 = noise; each lane owns 2
// adjacent expert columns (float2 w loads, 512B per wave-instruction, every
// cache line fully consumed). x[t][k] addresses depend only on blockIdx /
// loop indices -> scalar loads on the SMEM pipe, consumed as SGPR operands
// by v_fma (possibly fused to v_pk_fma_f32 on the float2 accumulators).
// k-split partials to disjoint ws regions; no atomics, no memset needed.
// ---------------------------------------------------------------------------
template <int KSPLIT, int TT>
__global__ __launch_bounds__(64) void router_gemm(
    const float* __restrict__ x,        // [NTOK][DD]
    const float* __restrict__ w_gate,   // [DD][EE]
    const float* __restrict__ w_noise,  // [DD][EE]
    float* __restrict__ part)           // [KSPLIT][NTOK][2*EE]
{
  constexpr int KR = DD / KSPLIT;

  const int lane = threadIdx.x;        // 0..63
  const int tok0 = blockIdx.x * TT;    // uniform
  const int ks   = blockIdx.y;         // uniform
  const int k0   = ks * KR;            // uniform
  const int le   = lane & 31;

  const float* __restrict__ W =
      ((lane & 32) ? w_noise : w_gate) + 2 * le + (size_t)k0 * EE;
  const float* __restrict__ xb = x + (size_t)tok0 * DD + k0;  // uniform base

  float2 acc[TT];
#pragma unroll
  for (int t = 0; t < TT; ++t) acc[t] = make_float2(0.0f, 0.0f);

  for (int k = 0; k < KR; k += 4) {
    float2 wv[4];
#pragma unroll
    for (int u = 0; u < 4; ++u)
      wv[u] = *reinterpret_cast<const float2*>(W + (size_t)(k + u) * EE);
#pragma unroll
    for (int t = 0; t < TT; ++t) {
      const float* __restrict__ xr = xb + (size_t)t * DD + k;  // uniform
#pragma unroll
      for (int u = 0; u < 4; ++u) {
        const float xs = xr[u];   // scalar load (uniform address)
        acc[t].x = fmaf(xs, wv[u].x, acc[t].x);
        acc[t].y = fmaf(xs, wv[u].y, acc[t].y);
      }
    }
  }

  // col index: gate expert 2*le(+1) at words 0..63, noise at words 64..127
  float* o = part + ((size_t)ks * NTOK + tok0) * (2 * EE) +
             ((lane & 32) ? EE : 0) + 2 * le;
#pragma unroll
  for (int t = 0; t < TT; ++t)
    *reinterpret_cast<float2*>(o + (size_t)t * (2 * EE)) = acc[t];
}

// ---------------------------------------------------------------------------
// Epilogue: one wave per token. Sum ksplit partials, softplus-noise, top-2
// (jax tie semantics: desc value, asc index), softmax over 2, scatter.
// ---------------------------------------------------------------------------
__global__ __launch_bounds__(256) void router_epilogue(
    const float* __restrict__ part,      // [ksplit][NTOK][2*EE]
    const float* __restrict__ noise_eps, // [NTOK][EE]
    float* __restrict__ out, int ksplit)
{
  const int t    = blockIdx.x * 4 + (threadIdx.x >> 6);
  const int lane = threadIdx.x & 63;

  float g = 0.0f, nraw = 0.0f;
  for (int s = 0; s < ksplit; ++s) {
    const float* p = part + ((size_t)s * NTOK + t) * (2 * EE);
    g    += p[lane];
    nraw += p[EE + lane];
  }
  const float ep = noise_eps[(size_t)t * EE + lane];

  // softplus(nraw) = max(nraw,0) + log1p(exp(-|nraw|))
  const float sp = fmaxf(nraw, 0.0f) + log1pf(expf(-fabsf(nraw)));
  const float z  = fmaf(sp, ep, g);

  // top-1 butterfly (all lanes converge)
  float v1 = z; int i1 = lane;
#pragma unroll
  for (int off = 32; off >= 1; off >>= 1) {
    const float ov = __shfl_xor(v1, off, 64);
    const int   oi = __shfl_xor(i1, off, 64);
    if (ov > v1 || (ov == v1 && oi < i1)) { v1 = ov; i1 = oi; }
  }
  // top-2: exclude winner
  float v2 = (lane == i1) ? -INFINITY : z; int i2 = lane;
#pragma unroll
  for (int off = 32; off >= 1; off >>= 1) {
    const float ov = __shfl_xor(v2, off, 64);
    const int   oi = __shfl_xor(i2, off, 64);
    if (ov > v2 || (ov == v2 && oi < i2)) { v2 = ov; i2 = oi; }
  }

  const float e2 = expf(v2 - v1);
  const float denom = 1.0f + e2;
  const float p1 = 1.0f / denom;
  const float p2 = e2 / denom;

  out[PROB_OFF + (size_t)t * EE + lane] =
      (lane == i1) ? p1 : ((lane == i2) ? p2 : 0.0f);

  if (lane == 0) {
    out[IDX_OFF + t * 2 + 0] = (float)i1;
    out[IDX_OFF + t * 2 + 1] = (float)i2;
  }

  out[MASK_OFF + 0 * MASK_K_STRIDE + (size_t)t * EE + lane] = (lane == i1) ? 1.0f : 0.0f;
  out[MASK_OFF + 1 * MASK_K_STRIDE + (size_t)t * EE + lane] = (lane == i2) ? 1.0f : 0.0f;
}

// ---------------------------------------------------------------------------
extern "C" void kernel_launch(void* const* d_in, const int* in_sizes, int n_in,
                              void* d_out, int out_size, void* d_ws, size_t ws_size,
                              hipStream_t stream) {
  const float* x   = (const float*)d_in[0];
  const float* eps = (const float*)d_in[1];
  const float* wg  = (const float*)d_in[2];
  const float* wn  = (const float*)d_in[3];
  float* out = (float*)d_out;
  float* ws  = (float*)d_ws;

  const size_t part_bytes = (size_t)NTOK * 2 * EE * sizeof(float);  // 4 MB/split

  int ksplit;
  if (ws_size >= 8 * part_bytes)      ksplit = 8;   // preferred: 4 waves/SIMD
  else if (ws_size >= 4 * part_bytes) ksplit = 4;
  else                                ksplit = 2;

  if (ksplit == 8) {
    // TT=16: 512 token-groups x 8 splits = 4096 single-wave blocks
    router_gemm<8, 16><<<dim3(NTOK / 16, 8), dim3(64), 0, stream>>>(x, wg, wn, ws);
  } else if (ksplit == 4) {
    // TT=8: 1024 token-groups x 4 splits = 4096 single-wave blocks
    router_gemm<4, 8><<<dim3(NTOK / 8, 4), dim3(64), 0, stream>>>(x, wg, wn, ws);
  } else {
    router_gemm<2, 8><<<dim3(NTOK / 8, 2), dim3(64), 0, stream>>>(x, wg, wn, ws);
  }

  router_epilogue<<<dim3(NTOK / 4), dim3(256), 0, stream>>>(ws, eps, out, ksplit);
}